// Round 1
// baseline (1996.840 us; speedup 1.0000x reference)
//
#include <hip/hip_runtime.h>
#include <math.h>

#define HH   128
#define H2   256
#define H3   384
#define NPT  65535      // nodes per tree (2^16 - 1)
#define NT   16         // nodes per workgroup in level kernel

__device__ __forceinline__ float fsig(float x)  { return 1.0f / (1.0f + __expf(-x)); }
__device__ __forceinline__ float ftanh(float x) { return 1.0f - 2.0f / (__expf(2.0f * x) + 1.0f); }

// ---------------- leaf frontier: elementwise only ----------------
__global__ __launch_bounds__(256) void leaf_k(
    const float* __restrict__ iou, const float* __restrict__ c_in,
    const float* __restrict__ b_iou,
    float* __restrict__ h_out, float* __restrict__ c_ws)
{
    int g    = blockIdx.x * 256 + threadIdx.x;   // one thread per 4 h-elems
    int node = g >> 5;                           // 131072 leaf nodes
    int e    = (g & 31) << 2;
    int tree = node >> 15;
    int loc  = 32767 + (node & 32767);
    size_t row = (size_t)tree * NPT + loc;

    const float* ip = iou + row * H3;
    float4 vi = *(const float4*)(ip + e);
    float4 vo = *(const float4*)(ip + HH + e);
    float4 vu = *(const float4*)(ip + 2 * HH + e);
    float4 vc = *(const float4*)(c_in + row * HH + e);
    float4 bi = *(const float4*)(b_iou + e);
    float4 bo = *(const float4*)(b_iou + HH + e);
    float4 bu = *(const float4*)(b_iou + 2 * HH + e);

    float4 hn, cn;
#define DO(X) { float iv = fsig(vi.X + bi.X); float ov = fsig(vo.X + bo.X); \
                float uv = ftanh(vu.X + bu.X); float cv = iv * uv + vc.X;   \
                cn.X = cv; hn.X = ov * ftanh(cv); }
    DO(x) DO(y) DO(z) DO(w)
#undef DO
    *(float4*)(h_out + row * HH + e) = hn;
    *(float4*)(c_ws  + row * HH + e) = cn;
}

// ---------------- internal level: gather children + matvec + gates ----------------
__global__ __launch_bounds__(256) void level_k(
    int lvl,
    const float* __restrict__ W_iou, const float* __restrict__ b_iou,
    const float* __restrict__ W_f,   const float* __restrict__ b_f,
    float* __restrict__ h_g, float* __restrict__ c_ws)
{
    // union: hc tile (16 KB) lives during the K-loop; pre buffer (40 KB) after.
    __shared__ __align__(16) float smem[NT * 640];
    float (*hc)[H2]  = (float (*)[H2])smem;
    float (*pre)[640] = (float (*)[640])smem;

    const int tid     = threadIdx.x;
    const int n_nodes = 4 << lvl;
    const int node0   = blockIdx.x * NT;
    const int loc0    = (1 << lvl) - 1;
    const int lmask   = (1 << lvl) - 1;

    // ---- load h_cat for NT nodes: hc[m][0:128]=h[left], hc[m][128:256]=h[right]
    for (int r = 0; r < 4; ++r) {
        int p = tid + 256 * r;        // float4 index into [NT][256]
        int m = p >> 6;
        int q = p & 63;
        int node = node0 + m;
        float4 v = make_float4(0.f, 0.f, 0.f, 0.f);
        if (node < n_nodes) {
            int tree = node >> lvl;
            int loc  = loc0 + (node & lmask);
            size_t crow = (size_t)tree * NPT + 2 * loc + 1;   // left child row
            int col = q * 4;
            const float* src = (col < HH) ? (h_g + crow * HH + col)
                                          : (h_g + (crow + 1) * HH + (col - HH));
            v = *(const float4*)src;
        }
        *(float4*)&hc[m][q * 4] = v;
    }
    __syncthreads();

    // ---- matvec: 640 output rows; thread owns j0=tid, j1=tid+256, (tid<128) j2=tid+512
    const int  j0   = tid;
    const int  j1   = tid + 256;
    const bool has2 = (tid < 128);
    const int  j2   = tid + 512;
    const float* w0 = (j0 < H3) ? (W_iou + (size_t)j0 * H2) : (W_f + (size_t)(j0 - H3) * H2);
    const float* w1 = (j1 < H3) ? (W_iou + (size_t)j1 * H2) : (W_f + (size_t)(j1 - H3) * H2);
    const float* w2 = W_f + (size_t)(has2 ? (j2 - H3) : 0) * H2;

    float acc0[NT], acc1[NT], acc2[NT];
#pragma unroll
    for (int m = 0; m < NT; ++m) { acc0[m] = 0.f; acc1[m] = 0.f; acc2[m] = 0.f; }

    for (int k = 0; k < H2; k += 4) {
        float4 a  = *(const float4*)(w0 + k);
        float4 b  = *(const float4*)(w1 + k);
        float4 cw = has2 ? *(const float4*)(w2 + k) : make_float4(0.f, 0.f, 0.f, 0.f);
#pragma unroll
        for (int m = 0; m < NT; ++m) {
            float4 hv = *(const float4*)&hc[m][k];
            acc0[m] += hv.x * a.x + hv.y * a.y + hv.z * a.z + hv.w * a.w;
            acc1[m] += hv.x * b.x + hv.y * b.y + hv.z * b.z + hv.w * b.w;
            if (has2)
                acc2[m] += hv.x * cw.x + hv.y * cw.y + hv.z * cw.z + hv.w * cw.w;
        }
    }
    __syncthreads();   // hc reads done; smem becomes `pre`

#pragma unroll
    for (int m = 0; m < NT; ++m) {
        pre[m][j0] = acc0[m];
        pre[m][j1] = acc1[m];
        if (has2) pre[m][j2] = acc2[m];
    }
    __syncthreads();

    // ---- epilogue: gates + c reduce + writeback
    for (int r = 0; r < 2; ++r) {
        int p = tid + 256 * r;        // float4 item over NT nodes x 32
        int m = p >> 5;
        int e = (p & 31) << 2;
        int node = node0 + m;
        if (node >= n_nodes) continue;
        int tree = node >> lvl;
        int loc  = loc0 + (node & lmask);
        size_t row  = (size_t)tree * NPT + loc;
        size_t lrow = (size_t)tree * NPT + 2 * loc + 1;

        float4 pi = *(const float4*)&pre[m][e];
        float4 po = *(const float4*)&pre[m][HH + e];
        float4 pu = *(const float4*)&pre[m][2 * HH + e];
        float4 pl = *(const float4*)&pre[m][H3 + e];
        float4 pr = *(const float4*)&pre[m][H3 + HH + e];
        float4 bi = *(const float4*)(b_iou + e);
        float4 bo = *(const float4*)(b_iou + HH + e);
        float4 bu = *(const float4*)(b_iou + 2 * HH + e);
        float4 bl = *(const float4*)(b_f + e);
        float4 br = *(const float4*)(b_f + HH + e);
        float4 cl = *(const float4*)(c_ws + lrow * HH + e);
        float4 cr = *(const float4*)(c_ws + (lrow + 1) * HH + e);

        float4 hn, cn;
#define DO(X) { float iv = fsig(pi.X + bi.X); float ov = fsig(po.X + bo.X);   \
                float uv = ftanh(pu.X + bu.X);                                \
                float fl = fsig(pl.X + bl.X); float fr = fsig(pr.X + br.X);   \
                float cv = iv * uv + fl * cl.X + fr * cr.X;                   \
                cn.X = cv; hn.X = ov * ftanh(cv); }
        DO(x) DO(y) DO(z) DO(w)
#undef DO
        *(float4*)(h_g  + row * HH + e) = hn;
        *(float4*)(c_ws + row * HH + e) = cn;
    }
}

extern "C" void kernel_launch(void* const* d_in, const int* in_sizes, int n_in,
                              void* d_out, int out_size, void* d_ws, size_t ws_size,
                              hipStream_t stream)
{
    const float* iou   = (const float*)d_in[0];
    const float* c_in  = (const float*)d_in[2];
    const float* W_iou = (const float*)d_in[3];
    const float* b_iou = (const float*)d_in[4];
    const float* W_f   = (const float*)d_in[5];
    const float* b_f   = (const float*)d_in[6];
    float* h_out = (float*)d_out;
    float* c_ws  = (float*)d_ws;    // T*128 floats = 128 MiB c-state scratch

    // leaves: 131072 nodes * 32 threads each
    leaf_k<<<16384, 256, 0, stream>>>(iou, c_in, b_iou, h_out, c_ws);

    // internal levels, bottom-up
    for (int l = 14; l >= 0; --l) {
        int n_nodes = 4 << l;
        int blocks  = (n_nodes + NT - 1) / NT;
        level_k<<<blocks, 256, 0, stream>>>(l, W_iou, b_iou, W_f, b_f, h_out, c_ws);
    }
}

// Round 2
// 1803.395 us; speedup vs baseline: 1.1073x; 1.1073x over previous
//
#include <hip/hip_runtime.h>
#include <math.h>

#define HH   128
#define H2   256
#define H3   384
#define NPT  65535      // nodes per tree (2^16 - 1)
#define NT   16         // nodes per workgroup in level kernel
#define TPB  320        // 5 waves; 640 rows = 2 per thread, uniform

__device__ __forceinline__ float fsig(float x)  { return 1.0f / (1.0f + __expf(-x)); }
__device__ __forceinline__ float ftanh(float x) { return 1.0f - 2.0f / (__expf(2.0f * x) + 1.0f); }

// ---------------- leaf frontier: elementwise only ----------------
__global__ __launch_bounds__(256) void leaf_k(
    const float* __restrict__ iou, const float* __restrict__ c_in,
    const float* __restrict__ b_iou,
    float* __restrict__ h_out, float* __restrict__ c_ws)
{
    int g    = blockIdx.x * 256 + threadIdx.x;   // one thread per 4 h-elems
    int node = g >> 5;                           // 131072 leaf nodes
    int e    = (g & 31) << 2;
    int tree = node >> 15;
    int loc  = 32767 + (node & 32767);
    size_t row = (size_t)tree * NPT + loc;

    const float* ip = iou + row * H3;
    float4 vi = *(const float4*)(ip + e);
    float4 vo = *(const float4*)(ip + HH + e);
    float4 vu = *(const float4*)(ip + 2 * HH + e);
    float4 vc = *(const float4*)(c_in + row * HH + e);
    float4 bi = *(const float4*)(b_iou + e);
    float4 bo = *(const float4*)(b_iou + HH + e);
    float4 bu = *(const float4*)(b_iou + 2 * HH + e);

    float4 hn, cn;
#define DO(X) { float iv = fsig(vi.X + bi.X); float ov = fsig(vo.X + bo.X); \
                float uv = ftanh(vu.X + bu.X); float cv = iv * uv + vc.X;   \
                cn.X = cv; hn.X = ov * ftanh(cv); }
    DO(x) DO(y) DO(z) DO(w)
#undef DO
    *(float4*)(h_out + row * HH + e) = hn;
    *(float4*)(c_ws  + row * HH + e) = cn;
}

// ---------------- internal level: gather children + matvec + gates ----------------
// 320 threads: each owns exactly 2 of the 640 output rows -> 32 accumulators,
// all live in arch VGPRs (launch_bounds gives the allocator 128 regs).
__global__ __launch_bounds__(TPB, 4) void level_k(
    int lvl,
    const float* __restrict__ W_iou, const float* __restrict__ b_iou,
    const float* __restrict__ W_f,   const float* __restrict__ b_f,
    float* __restrict__ h_g, float* __restrict__ c_ws)
{
    // union: hc tile (16 KB) lives during the K-loop; pre buffer (40 KB) after.
    __shared__ __align__(16) float smem[NT * 640];
    float (*hc)[H2]   = (float (*)[H2])smem;
    float (*pre)[640] = (float (*)[640])smem;

    const int tid     = threadIdx.x;
    const int n_nodes = 4 << lvl;
    const int node0   = blockIdx.x * NT;
    const int loc0    = (1 << lvl) - 1;
    const int lmask   = (1 << lvl) - 1;

    // ---- load h_cat for NT nodes: hc[m][0:128]=h[left], hc[m][128:256]=h[right]
    for (int r = 0; r < 4; ++r) {
        int p = tid + TPB * r;        // float4 index into [NT][256]
        if (p < NT * 64) {
            int m = p >> 6;
            int q = p & 63;
            int node = node0 + m;
            float4 v = make_float4(0.f, 0.f, 0.f, 0.f);
            if (node < n_nodes) {
                int tree = node >> lvl;
                int loc  = loc0 + (node & lmask);
                size_t crow = (size_t)tree * NPT + 2 * loc + 1;   // left child row
                int col = q * 4;
                const float* src = (col < HH) ? (h_g + crow * HH + col)
                                              : (h_g + (crow + 1) * HH + (col - HH));
                v = *(const float4*)src;
            }
            *(float4*)&hc[m][q * 4] = v;
        }
    }
    __syncthreads();

    // ---- matvec: 640 output rows; thread owns rows j0=tid, j1=tid+320
    const int j0 = tid;                // always < 384 -> W_iou
    const int j1 = tid + TPB;          // 320..639: W_iou if <384 else W_f
    const float* w0 = W_iou + (size_t)j0 * H2;
    const float* w1 = (j1 < H3) ? (W_iou + (size_t)j1 * H2)
                                : (W_f + (size_t)(j1 - H3) * H2);

    float acc0[NT], acc1[NT];
#pragma unroll
    for (int m = 0; m < NT; ++m) { acc0[m] = 0.f; acc1[m] = 0.f; }

    for (int k = 0; k < H2; k += 4) {
        float4 a = *(const float4*)(w0 + k);
        float4 b = *(const float4*)(w1 + k);
#pragma unroll
        for (int m = 0; m < NT; ++m) {
            float4 hv = *(const float4*)&hc[m][k];
            acc0[m] += hv.x * a.x + hv.y * a.y + hv.z * a.z + hv.w * a.w;
            acc1[m] += hv.x * b.x + hv.y * b.y + hv.z * b.z + hv.w * b.w;
        }
    }
    __syncthreads();   // hc reads done; smem becomes `pre`

#pragma unroll
    for (int m = 0; m < NT; ++m) {
        pre[m][j0] = acc0[m];
        pre[m][j1] = acc1[m];
    }
    __syncthreads();

    // ---- epilogue: gates + c reduce + writeback (NT*32 = 512 float4 items)
    for (int r = 0; r < 2; ++r) {
        int p = tid + TPB * r;
        if (p >= NT * 32) continue;
        int m = p >> 5;
        int e = (p & 31) << 2;
        int node = node0 + m;
        if (node >= n_nodes) continue;
        int tree = node >> lvl;
        int loc  = loc0 + (node & lmask);
        size_t row  = (size_t)tree * NPT + loc;
        size_t lrow = (size_t)tree * NPT + 2 * loc + 1;

        float4 pi = *(const float4*)&pre[m][e];
        float4 po = *(const float4*)&pre[m][HH + e];
        float4 pu = *(const float4*)&pre[m][2 * HH + e];
        float4 pl = *(const float4*)&pre[m][H3 + e];
        float4 pr = *(const float4*)&pre[m][H3 + HH + e];
        float4 bi = *(const float4*)(b_iou + e);
        float4 bo = *(const float4*)(b_iou + HH + e);
        float4 bu = *(const float4*)(b_iou + 2 * HH + e);
        float4 bl = *(const float4*)(b_f + e);
        float4 br = *(const float4*)(b_f + HH + e);
        float4 cl = *(const float4*)(c_ws + lrow * HH + e);
        float4 cr = *(const float4*)(c_ws + (lrow + 1) * HH + e);

        float4 hn, cn;
#define DO(X) { float iv = fsig(pi.X + bi.X); float ov = fsig(po.X + bo.X);   \
                float uv = ftanh(pu.X + bu.X);                                \
                float fl = fsig(pl.X + bl.X); float fr = fsig(pr.X + br.X);   \
                float cv = iv * uv + fl * cl.X + fr * cr.X;                   \
                cn.X = cv; hn.X = ov * ftanh(cv); }
        DO(x) DO(y) DO(z) DO(w)
#undef DO
        *(float4*)(h_g  + row * HH + e) = hn;
        *(float4*)(c_ws + row * HH + e) = cn;
    }
}

extern "C" void kernel_launch(void* const* d_in, const int* in_sizes, int n_in,
                              void* d_out, int out_size, void* d_ws, size_t ws_size,
                              hipStream_t stream)
{
    const float* iou   = (const float*)d_in[0];
    const float* c_in  = (const float*)d_in[2];
    const float* W_iou = (const float*)d_in[3];
    const float* b_iou = (const float*)d_in[4];
    const float* W_f   = (const float*)d_in[5];
    const float* b_f   = (const float*)d_in[6];
    float* h_out = (float*)d_out;
    float* c_ws  = (float*)d_ws;    // T*128 floats = 128 MiB c-state scratch

    // leaves: 131072 nodes * 32 threads each
    leaf_k<<<16384, 256, 0, stream>>>(iou, c_in, b_iou, h_out, c_ws);

    // internal levels, bottom-up
    for (int l = 14; l >= 0; --l) {
        int n_nodes = 4 << l;
        int blocks  = (n_nodes + NT - 1) / NT;
        level_k<<<blocks, TPB, 0, stream>>>(l, W_iou, b_iou, W_f, b_f, h_out, c_ws);
    }
}

// Round 3
// 525.272 us; speedup vs baseline: 3.8015x; 3.4333x over previous
//
#include <hip/hip_runtime.h>
#include <math.h>

#define HH   128
#define H2   256
#define H3   384
#define NPT  65535      // nodes per tree (2^16 - 1)
#define MT   32         // nodes per block in level kernel
#define TPB  256        // 4 waves

typedef __bf16 bf16x8 __attribute__((ext_vector_type(8)));
typedef float  f32x4  __attribute__((ext_vector_type(4)));

__device__ unsigned short Wb_g[640 * 256];   // bf16 [row=output col j][k], j<384: W_iou, else W_f

__device__ __forceinline__ float fsig(float x)  { return 1.0f / (1.0f + __expf(-x)); }
__device__ __forceinline__ float ftanh(float x) { return 1.0f - 2.0f / (__expf(2.0f * x) + 1.0f); }
__device__ __forceinline__ unsigned short f2bf(float f) {   // RNE fp32->bf16
    unsigned u = __float_as_uint(f);
    u += 0x7fffu + ((u >> 16) & 1u);
    return (unsigned short)(u >> 16);
}

// ---------------- weight convert: fp32 -> bf16, once per launch ----------------
__global__ __launch_bounds__(256) void conv_k(const float* __restrict__ W_iou,
                                              const float* __restrict__ W_f)
{
    int t    = blockIdx.x * 256 + threadIdx.x;   // 40960 threads, 4 elems each
    int base = t * 4;                            // element index into [640][256]
    int j = base >> 8, k = base & 255;
    const float* src = (j < H3) ? (W_iou + (size_t)j * H2 + k)
                                : (W_f + (size_t)(j - H3) * H2 + k);
    float4 v = *(const float4*)src;
    ushort4 p;
    p.x = f2bf(v.x); p.y = f2bf(v.y); p.z = f2bf(v.z); p.w = f2bf(v.w);
    *(ushort4*)(Wb_g + base) = p;
}

// ---------------- leaf frontier: elementwise only ----------------
__global__ __launch_bounds__(256) void leaf_k(
    const float* __restrict__ iou, const float* __restrict__ c_in,
    const float* __restrict__ b_iou,
    float* __restrict__ h_out, float* __restrict__ c_ws)
{
    int g    = blockIdx.x * 256 + threadIdx.x;
    int node = g >> 5;                           // 131072 leaf nodes
    int e    = (g & 31) << 2;
    int tree = node >> 15;
    int loc  = 32767 + (node & 32767);
    size_t row = (size_t)tree * NPT + loc;

    const float* ip = iou + row * H3;
    float4 vi = *(const float4*)(ip + e);
    float4 vo = *(const float4*)(ip + HH + e);
    float4 vu = *(const float4*)(ip + 2 * HH + e);
    float4 vc = *(const float4*)(c_in + row * HH + e);
    float4 bi = *(const float4*)(b_iou + e);
    float4 bo = *(const float4*)(b_iou + HH + e);
    float4 bu = *(const float4*)(b_iou + 2 * HH + e);

    float4 hn, cn;
#define DO(X) { float iv = fsig(vi.X + bi.X); float ov = fsig(vo.X + bo.X); \
                float uv = ftanh(vu.X + bu.X); float cv = iv * uv + vc.X;   \
                cn.X = cv; hn.X = ov * ftanh(cv); }
    DO(x) DO(y) DO(z) DO(w)
#undef DO
    *(float4*)(h_out + row * HH + e) = hn;
    *(float4*)(c_ws  + row * HH + e) = cn;
}

// ---------------- internal level: MFMA matvec + fused gates ----------------
// 256 threads = 4 waves. Block computes 32 nodes x 640 outputs.
// Wave w owns output cols [32w,32w+32) of EACH of the 5 gate blocks, so the
// epilogue for any output element is entirely lane-local (no pre-act LDS).
__global__ __launch_bounds__(TPB, 2) void level_k(
    int lvl,
    const float* __restrict__ b_iou, const float* __restrict__ b_f,
    float* __restrict__ h_g, float* __restrict__ c_ws)
{
    __shared__ __align__(16) unsigned short A_lds[MT * H2];   // 16 KB bf16, swizzled

    const int tid  = threadIdx.x;
    const int lane = tid & 63;
    const int w    = tid >> 6;             // wave 0..3
    const int lr   = lane & 15;
    const int lc   = lane >> 4;
    const int n_nodes = 4 << lvl;
    const int node0   = blockIdx.x * MT;
    const int loc0    = (1 << lvl) - 1;
    const int lmask   = loc0;

    // ---- stage A = h_cat[32 nodes][256] as bf16 into swizzled LDS ----
    // A[m][k] = h[left(m)][k] (k<128) / h[right(m)][k-128]; children rows = 2*node+1, +2.
#pragma unroll
    for (int it = 0; it < 8; ++it) {
        int item = tid + TPB * it;         // item over [32 m][64 float4-units]
        int m = item >> 6, q = item & 63;
        int node = node0 + m;
        uint2 pk = make_uint2(0u, 0u);
        if (node < n_nodes) {
            int tree = node >> lvl;
            int loc  = loc0 + (node & lmask);
            size_t crow = (size_t)tree * NPT + 2 * loc + 1 + (q >> 5);
            float4 v = *(const float4*)(h_g + crow * HH + (q & 31) * 4);
            pk.x = (unsigned)f2bf(v.x) | ((unsigned)f2bf(v.y) << 16);
            pk.y = (unsigned)f2bf(v.z) | ((unsigned)f2bf(v.w) << 16);
        }
        int byte = (m * 512 + q * 8) ^ ((m & 7) << 4);
        *(uint2*)((char*)A_lds + byte) = pk;
    }
    __syncthreads();

    // ---- MFMA K-loop: acc[mt][gate][sub], 80 f32 regs ----
    f32x4 acc[2][5][2] = {};
    const unsigned short* Wp = Wb_g + (size_t)lr * H2 + lc * 8;

#pragma unroll 2
    for (int kk = 0; kk < 8; ++kk) {
        bf16x8 a0, a1;
        {
            int row = lr;
            int byte = (row * 512 + kk * 64 + lc * 16) ^ ((row & 7) << 4);
            a0 = *(const bf16x8*)((const char*)A_lds + byte);
        }
        {
            int row = 16 + lr;
            int byte = (row * 512 + kk * 64 + lc * 16) ^ ((row & 7) << 4);
            a1 = *(const bf16x8*)((const char*)A_lds + byte);
        }
#pragma unroll
        for (int g = 0; g < 5; ++g) {
#pragma unroll
            for (int sub = 0; sub < 2; ++sub) {
                int nrow = g * HH + w * 32 + sub * 16;   // B rows (output cols)
                bf16x8 b = *(const bf16x8*)(Wp + (size_t)nrow * H2 + kk * 32);
                acc[0][g][sub] = __builtin_amdgcn_mfma_f32_16x16x32_bf16(a0, b, acc[0][g][sub], 0, 0, 0);
                acc[1][g][sub] = __builtin_amdgcn_mfma_f32_16x16x32_bf16(a1, b, acc[1][g][sub], 0, 0, 0);
            }
        }
    }

    // ---- epilogue: all 5 gates lane-local. C/D: col=lane&15, row=(lane>>4)*4+r ----
#pragma unroll
    for (int mt = 0; mt < 2; ++mt) {
#pragma unroll
        for (int r = 0; r < 4; ++r) {
            int node = node0 + mt * 16 + lc * 4 + r;
            if (node >= n_nodes) continue;
            int tree = node >> lvl;
            int loc  = loc0 + (node & lmask);
            size_t row  = (size_t)tree * NPT + loc;
            size_t lrow = (size_t)tree * NPT + 2 * loc + 1;
#pragma unroll
            for (int sub = 0; sub < 2; ++sub) {
                int ee = w * 32 + sub * 16 + lr;
                float pi = acc[mt][0][sub][r] + b_iou[ee];
                float po = acc[mt][1][sub][r] + b_iou[HH + ee];
                float pu = acc[mt][2][sub][r] + b_iou[2 * HH + ee];
                float pl = acc[mt][3][sub][r] + b_f[ee];
                float pr = acc[mt][4][sub][r] + b_f[HH + ee];
                float cl = c_ws[lrow * HH + ee];
                float cr = c_ws[(lrow + 1) * HH + ee];
                float cv = fsig(pi) * ftanh(pu) + fsig(pl) * cl + fsig(pr) * cr;
                float hv = fsig(po) * ftanh(cv);
                h_g[row * HH + ee]  = hv;
                c_ws[row * HH + ee] = cv;
            }
        }
    }
}

extern "C" void kernel_launch(void* const* d_in, const int* in_sizes, int n_in,
                              void* d_out, int out_size, void* d_ws, size_t ws_size,
                              hipStream_t stream)
{
    const float* iou   = (const float*)d_in[0];
    const float* c_in  = (const float*)d_in[2];
    const float* W_iou = (const float*)d_in[3];
    const float* b_iou = (const float*)d_in[4];
    const float* W_f   = (const float*)d_in[5];
    const float* b_f   = (const float*)d_in[6];
    float* h_out = (float*)d_out;
    float* c_ws  = (float*)d_ws;    // T*128 floats = 128 MiB c-state scratch

    conv_k<<<160, 256, 0, stream>>>(W_iou, W_f);
    leaf_k<<<16384, 256, 0, stream>>>(iou, c_in, b_iou, h_out, c_ws);

    for (int l = 14; l >= 0; --l) {
        int n_nodes = 4 << l;
        int blocks  = (n_nodes + MT - 1) / MT;
        level_k<<<blocks, TPB, 0, stream>>>(l, b_iou, b_f, h_out, c_ws);
    }
}

// Round 4
// 446.739 us; speedup vs baseline: 4.4698x; 1.1758x over previous
//
#include <hip/hip_runtime.h>
#include <math.h>

#define HH   128
#define H2   256
#define H3   384
#define NPT  65535      // nodes per tree (2^16 - 1)
#define MT   32         // nodes per block in level kernel
#define TPB  512        // 8 waves

typedef __bf16 bf16x8 __attribute__((ext_vector_type(8)));
typedef float  f32x4  __attribute__((ext_vector_type(4)));

__device__ unsigned short Wb_g[640 * 256];   // bf16 [row=output col j][k]; j<384: W_iou, else W_f

__device__ __forceinline__ float fsig(float x)  { return 1.0f / (1.0f + __expf(-x)); }
__device__ __forceinline__ float ftanh(float x) { return 1.0f - 2.0f / (__expf(2.0f * x) + 1.0f); }
__device__ __forceinline__ unsigned short f2bf(float f) {   // RNE fp32->bf16
    unsigned u = __float_as_uint(f);
    u += 0x7fffu + ((u >> 16) & 1u);
    return (unsigned short)(u >> 16);
}

// ---------------- weight convert: fp32 -> bf16, once per launch ----------------
__global__ __launch_bounds__(256) void conv_k(const float* __restrict__ W_iou,
                                              const float* __restrict__ W_f)
{
    int t    = blockIdx.x * 256 + threadIdx.x;   // 40960 threads, 4 elems each
    int base = t * 4;                            // element index into [640][256]
    int j = base >> 8, k = base & 255;
    const float* src = (j < H3) ? (W_iou + (size_t)j * H2 + k)
                                : (W_f + (size_t)(j - H3) * H2 + k);
    float4 v = *(const float4*)src;
    ushort4 p;
    p.x = f2bf(v.x); p.y = f2bf(v.y); p.z = f2bf(v.z); p.w = f2bf(v.w);
    *(ushort4*)(Wb_g + base) = p;
}

// ---------------- leaf frontier: elementwise only ----------------
__global__ __launch_bounds__(256) void leaf_k(
    const float* __restrict__ iou, const float* __restrict__ c_in,
    const float* __restrict__ b_iou,
    float* __restrict__ h_out, float* __restrict__ c_ws,
    unsigned short* __restrict__ h_bf)
{
    int g    = blockIdx.x * 256 + threadIdx.x;
    int node = g >> 5;                           // 131072 leaf nodes
    int e    = (g & 31) << 2;
    int tree = node >> 15;
    int loc  = 32767 + (node & 32767);
    size_t row = (size_t)tree * NPT + loc;

    const float* ip = iou + row * H3;
    float4 vi = *(const float4*)(ip + e);
    float4 vo = *(const float4*)(ip + HH + e);
    float4 vu = *(const float4*)(ip + 2 * HH + e);
    float4 vc = *(const float4*)(c_in + row * HH + e);
    float4 bi = *(const float4*)(b_iou + e);
    float4 bo = *(const float4*)(b_iou + HH + e);
    float4 bu = *(const float4*)(b_iou + 2 * HH + e);

    float4 hn, cn;
#define DO(X) { float iv = fsig(vi.X + bi.X); float ov = fsig(vo.X + bo.X); \
                float uv = ftanh(vu.X + bu.X); float cv = iv * uv + vc.X;   \
                cn.X = cv; hn.X = ov * ftanh(cv); }
    DO(x) DO(y) DO(z) DO(w)
#undef DO
    *(float4*)(h_out + row * HH + e) = hn;
    *(float4*)(c_ws  + row * HH + e) = cn;
    ushort4 hb;
    hb.x = f2bf(hn.x); hb.y = f2bf(hn.y); hb.z = f2bf(hn.z); hb.w = f2bf(hn.w);
    *(ushort4*)(h_bf + row * HH + e) = hb;
}

// ---------------- internal level: MFMA matvec + fused gates ----------------
// 512 threads = 8 waves. Block computes 32 nodes x 640 outputs.
// Wave w owns output cols [16w,16w+16) of EACH of the 5 gate blocks, so the
// epilogue for any output element is entirely lane-local.
__global__ __launch_bounds__(TPB, 4) void level_k(
    int lvl,
    const float* __restrict__ b_iou, const float* __restrict__ b_f,
    float* __restrict__ h_g, float* __restrict__ c_ws,
    unsigned short* __restrict__ h_bf)
{
    __shared__ __align__(16) unsigned short A_lds[MT * H2];   // 16 KB bf16, swizzled

    const int tid  = threadIdx.x;
    const int lane = tid & 63;
    const int w    = tid >> 6;             // wave 0..7
    const int lr   = lane & 15;
    const int lc   = lane >> 4;
    const int n_nodes = 4 << lvl;
    const int node0   = blockIdx.x * MT;
    const int loc0    = (1 << lvl) - 1;
    const int lmask   = loc0;

    // ---- stage A = h_cat[32 nodes][256] bf16 into swizzled LDS (reads h_bf) ----
#pragma unroll
    for (int it = 0; it < 2; ++it) {
        int item = tid + TPB * it;         // item over [32 m][32 x 16B-units]
        int m = item >> 5, u = item & 31;
        int node = node0 + m;
        uint4 v = make_uint4(0u, 0u, 0u, 0u);
        if (node < n_nodes) {
            int tree = node >> lvl;
            int loc  = loc0 + (node & lmask);
            size_t crow = (size_t)tree * NPT + 2 * loc + 1 + (u >> 4);
            v = *(const uint4*)(h_bf + crow * HH + (u & 15) * 8);
        }
        int byte = (m * 512 + u * 16) ^ ((m & 7) << 4);
        *(uint4*)((char*)A_lds + byte) = v;
    }
    __syncthreads();

    // ---- MFMA K-loop: acc[mt][gate], 40 f32 regs ----
    f32x4 acc[2][5] = {};
    const unsigned short* Wp = Wb_g + (size_t)(w * 16 + lr) * H2 + lc * 8;

#pragma unroll 2
    for (int kk = 0; kk < 8; ++kk) {
        bf16x8 a0, a1;
        {
            int row = lr;
            int byte = (row * 512 + kk * 64 + lc * 16) ^ ((row & 7) << 4);
            a0 = *(const bf16x8*)((const char*)A_lds + byte);
        }
        {
            int row = 16 + lr;
            int byte = (row * 512 + kk * 64 + lc * 16) ^ ((row & 7) << 4);
            a1 = *(const bf16x8*)((const char*)A_lds + byte);
        }
#pragma unroll
        for (int g = 0; g < 5; ++g) {
            bf16x8 b = *(const bf16x8*)(Wp + (size_t)g * HH * H2 + kk * 32);
            acc[0][g] = __builtin_amdgcn_mfma_f32_16x16x32_bf16(a0, b, acc[0][g], 0, 0, 0);
            acc[1][g] = __builtin_amdgcn_mfma_f32_16x16x32_bf16(a1, b, acc[1][g], 0, 0, 0);
        }
    }

    // ---- epilogue: lane-local gates. C/D: col=lane&15, row=(lane>>4)*4+r ----
    const int ee = w * 16 + lr;
    const float bi = b_iou[ee], bo = b_iou[HH + ee], bu = b_iou[2 * HH + ee];
    const float bl = b_f[ee],   br = b_f[HH + ee];

#pragma unroll
    for (int mt = 0; mt < 2; ++mt) {
#pragma unroll
        for (int r = 0; r < 4; ++r) {
            int node = node0 + mt * 16 + lc * 4 + r;
            if (node >= n_nodes) continue;
            int tree = node >> lvl;
            int loc  = loc0 + (node & lmask);
            size_t row  = (size_t)tree * NPT + loc;
            size_t lrow = (size_t)tree * NPT + 2 * loc + 1;

            float pi = acc[mt][0][r] + bi;
            float po = acc[mt][1][r] + bo;
            float pu = acc[mt][2][r] + bu;
            float pl = acc[mt][3][r] + bl;
            float pr = acc[mt][4][r] + br;
            float cl = c_ws[lrow * HH + ee];
            float cr = c_ws[(lrow + 1) * HH + ee];
            float cv = fsig(pi) * ftanh(pu) + fsig(pl) * cl + fsig(pr) * cr;
            float hv = fsig(po) * ftanh(cv);
            h_g[row * HH + ee]  = hv;
            c_ws[row * HH + ee] = cv;
            h_bf[row * HH + ee] = f2bf(hv);
        }
    }
}

extern "C" void kernel_launch(void* const* d_in, const int* in_sizes, int n_in,
                              void* d_out, int out_size, void* d_ws, size_t ws_size,
                              hipStream_t stream)
{
    const float* iou   = (const float*)d_in[0];
    const float* c_in  = (const float*)d_in[2];
    const float* W_iou = (const float*)d_in[3];
    const float* b_iou = (const float*)d_in[4];
    const float* W_f   = (const float*)d_in[5];
    const float* b_f   = (const float*)d_in[6];
    float* h_out = (float*)d_out;
    float* c_ws  = (float*)d_ws;                                   // 134 MiB fp32 c
    unsigned short* h_bf = (unsigned short*)((char*)d_ws + (size_t)136 * 1024 * 1024);  // 67 MiB bf16 h

    conv_k<<<160, 256, 0, stream>>>(W_iou, W_f);
    leaf_k<<<16384, 256, 0, stream>>>(iou, c_in, b_iou, h_out, c_ws, h_bf);

    for (int l = 14; l >= 0; --l) {
        int n_nodes = 4 << l;
        int blocks  = (n_nodes + MT - 1) / MT;
        level_k<<<blocks, TPB, 0, stream>>>(l, b_iou, b_f, h_out, c_ws, h_bf);
    }
}